// Round 5
// baseline (911.876 us; speedup 1.0000x reference)
//
#include <hip/hip_runtime.h>
#include <hip/hip_bf16.h>

// Problem constants (fixed by the reference's setup_inputs)
#define NNODES   100000
#define INF      256
#define OUTF     128
#define NLAYERS  3        // n_layers input is a device scalar, constant 3 per spec

#define SCAN_BLK 1024     // rows per scan block (256 thr x 4)
#define NSB      ((NNODES + SCAN_BLK - 1) / SCAN_BLK)   // 98

typedef unsigned short u16;

typedef __attribute__((ext_vector_type(8))) __bf16 bf16x8;
typedef __attribute__((ext_vector_type(4))) float  f32x4;

__device__ __forceinline__ float bf2f(u16 u) {
    union { unsigned int i; float f; } c; c.i = ((unsigned int)u) << 16; return c.f;
}
__device__ __forceinline__ u16 f2bf(float f) {   // round-to-nearest-even
    union { float f; unsigned int i; } c; c.f = f;
    unsigned int lsb = (c.i >> 16) & 1;
    return (u16)((c.i + 0x7FFF + lsb) >> 16);
}

// ---------------- stage 0: W fp32 -> bf16 (once) ----------------
__global__ __launch_bounds__(256) void wconv_kernel(const float* __restrict__ W,
                                                    u16* __restrict__ Wbf) {
    int i = (blockIdx.x * 256 + threadIdx.x) * 4;
    float4 a = *(const float4*)(W + i);
    ushort4 o;
    o.x = f2bf(a.x); o.y = f2bf(a.y); o.z = f2bf(a.z); o.w = f2bf(a.w);
    *(ushort4*)(Wbf + i) = o;    // Wbf is 16B-aligned (see kernel_launch layout)
}

// ---------------- CSR build: direct global-atomic counting sort ----------
// deg[] (= rowcnt) lives in 400KB -> L2-resident; 3.2M fire-and-forget
// atomics (count) + 3.2M returning atomics (scatter). Row starts padded to
// even record offsets so spmm's int4 edge-record loads stay 16B-aligned.

__global__ __launch_bounds__(256) void count_kernel(const int* __restrict__ row,
                                                    int* __restrict__ deg, int E)
{
    int e = (blockIdx.x * 256 + threadIdx.x) * 4;
    if (e + 3 < E) {
        int4 r4 = *(const int4*)(row + e);
        atomicAdd(&deg[r4.x], 1);
        atomicAdd(&deg[r4.y], 1);
        atomicAdd(&deg[r4.z], 1);
        atomicAdd(&deg[r4.w], 1);
    } else {
        for (; e < E; ++e) atomicAdd(&deg[row[e]], 1);
    }
}

// scan stage 1: per-block exclusive scan of even-padded degrees.
// rowptr[r] <- block-local exclusive prefix; btot[blk] <- block total.
__global__ __launch_bounds__(256) void scan1_kernel(const int* __restrict__ deg,
                                                    int* __restrict__ rowptr,
                                                    int* __restrict__ btot, int M)
{
    __shared__ int sc[256];
    int tid = threadIdx.x;
    int r0  = blockIdx.x * SCAN_BLK + tid * 4;
    int w[4]; int s = 0;
#pragma unroll
    for (int i = 0; i < 4; ++i) {
        int r = r0 + i;
        int d = (r < M) ? deg[r] : 0;
        w[i] = s;                      // thread-local exclusive prefix
        s += (d + 1) & ~1;             // pad each row to even record count
    }
    sc[tid] = s;
    __syncthreads();
    for (int off = 1; off < 256; off <<= 1) {   // Hillis-Steele inclusive
        int t = (tid >= off) ? sc[tid - off] : 0;
        __syncthreads();
        sc[tid] += t;
        __syncthreads();
    }
    int bex = sc[tid] - s;             // block-local exclusive prefix
#pragma unroll
    for (int i = 0; i < 4; ++i) {
        int r = r0 + i;
        if (r < M) rowptr[r] = bex + w[i];
    }
    if (tid == 0) btot[blockIdx.x] = sc[255];
}

// scan stage 2: single block scans the 98 block totals (exclusive, in place).
__global__ __launch_bounds__(128) void scan2_kernel(int* __restrict__ btot)
{
    __shared__ int sc[128];
    int tid = threadIdx.x;
    int v = (tid < NSB) ? btot[tid] : 0;
    sc[tid] = v;
    __syncthreads();
    for (int off = 1; off < 128; off <<= 1) {
        int t = (tid >= off) ? sc[tid - off] : 0;
        __syncthreads();
        sc[tid] += t;
        __syncthreads();
    }
    if (tid < NSB) btot[tid] = sc[tid] - v;     // exclusive
}

// scan stage 3: add block bases; init write cursors.
__global__ __launch_bounds__(256) void scan3_kernel(int* __restrict__ rowptr,
                                                    int* __restrict__ cursor,
                                                    const int* __restrict__ btot, int M)
{
    int base = btot[blockIdx.x];
    int r0   = blockIdx.x * SCAN_BLK + threadIdx.x * 4;
#pragma unroll
    for (int i = 0; i < 4; ++i) {
        int r = r0 + i;
        if (r < M) {
            int p = rowptr[r] + base;
            rowptr[r] = p;
            cursor[r] = p;
        }
    }
}

// scatter: pos = atomicAdd(cursor[row]) -> epart[pos] = (col, val).
// Pure col stored (no bit packing); within-row order = arrival order.
__global__ __launch_bounds__(256) void scatter_kernel(
    const int* __restrict__ row, const int* __restrict__ col,
    const float* __restrict__ vals, int* __restrict__ cursor,
    int2* __restrict__ epart, int E)
{
    int e = (blockIdx.x * 256 + threadIdx.x) * 4;
    if (e + 3 < E) {
        int4   r4 = *(const int4*)(row + e);
        int4   c4 = *(const int4*)(col + e);
        float4 v4 = *(const float4*)(vals + e);
        int p0 = atomicAdd(&cursor[r4.x], 1);
        int p1 = atomicAdd(&cursor[r4.y], 1);
        int p2 = atomicAdd(&cursor[r4.z], 1);
        int p3 = atomicAdd(&cursor[r4.w], 1);
        epart[p0] = make_int2(c4.x, __float_as_int(v4.x));
        epart[p1] = make_int2(c4.y, __float_as_int(v4.y));
        epart[p2] = make_int2(c4.z, __float_as_int(v4.z));
        epart[p3] = make_int2(c4.w, __float_as_int(v4.w));
    } else {
        for (; e < E; ++e) {
            int p = atomicAdd(&cursor[row[e]], 1);
            epart[p] = make_int2(col[e], __float_as_int(vals[e]));
        }
    }
}

// ---------------- dense linear via MFMA: z = bf16(x W^T + b) ----------------
// 256 threads = 4 waves; block covers 64 rows x 128 cols; K=256 in 8 steps of
// mfma_f32_16x16x32_bf16. Pre-converted Wbf is staged to a 64KB XOR-swizzled
// LDS image with 16 x ds_write_b128 per thread (swizzle permutes 16B chunks:
// chunk j -> j ^ (c&7), matching the read side). x fragments load directly
// from global and convert in-register; no barriers in the K-loop.
// Fragment maps (gfx950, verified):
//   A: row = lane&15, k = 8*(lane>>4)+e   B: col = lane&15, same k
//   D: col = lane&15, row = 4*(lane>>4)+reg
__global__ __launch_bounds__(256) void gemm_mfma_kernel(
    const float* __restrict__ x, const u16* __restrict__ Wbf,
    const float* __restrict__ b, u16* __restrict__ z, int M)
{
    __shared__ __align__(16) u16 Wl[128 * 256];   // 64 KB bf16, swizzled
    int tid  = threadIdx.x;
    int lane = tid & 63;
    int wv   = tid >> 6;

    // ---- stage Wbf: 128x256 bf16 -> LDS, vectorized (one-time) ----
    {
        int c = tid >> 1;              // row 0..127
        int h = tid & 1;               // half
        const bf16x8* src = (const bf16x8*)(Wbf + c * 256 + h * 128);
        u16* dst = Wl + c * 256;
        int swz = c & 7;               // XOR on 16B-chunk index
#pragma unroll
        for (int t = 0; t < 16; ++t) {
            int j = h * 16 + t;        // chunk index 0..31
            *(bf16x8*)(dst + 8 * (j ^ swz)) = src[t];
        }
    }

    int cl = lane & 15;
    int g  = lane >> 4;
    float bo[8];
#pragma unroll
    for (int f = 0; f < 8; ++f) bo[f] = b[16 * f + cl];   // bias per col-frag

    __syncthreads();

    int n0 = blockIdx.x * 64 + wv * 16;    // this wave's 16-row tile
    int nr = n0 + cl;                      // A-operand row for this lane
    if (nr >= M) nr = M - 1;               // clamp (dup loads ok, stores guarded)
    const float* xrow = x + (size_t)nr * INF + 8 * g;

    f32x4 acc[8];
#pragma unroll
    for (int f = 0; f < 8; ++f) {
        f32x4 a; a[0] = bo[f]; a[1] = bo[f]; a[2] = bo[f]; a[3] = bo[f];
        acc[f] = a;
    }

#pragma unroll
    for (int ks = 0; ks < 8; ++ks) {
        int k0 = ks * 32;
        float4 a0 = ((const float4*)(xrow + k0))[0];
        float4 a1 = ((const float4*)(xrow + k0))[1];
        bf16x8 af;
        af[0] = (__bf16)a0.x; af[1] = (__bf16)a0.y;
        af[2] = (__bf16)a0.z; af[3] = (__bf16)a0.w;
        af[4] = (__bf16)a1.x; af[5] = (__bf16)a1.y;
        af[6] = (__bf16)a1.z; af[7] = (__bf16)a1.w;
#pragma unroll
        for (int f = 0; f < 8; ++f) {
            int c  = 16 * f + cl;
            int ke = (k0 + 8 * g) ^ ((c & 7) << 3);
            bf16x8 bfr = *(const bf16x8*)(Wl + c * 256 + ke);
            acc[f] = __builtin_amdgcn_mfma_f32_16x16x32_bf16(af, bfr, acc[f], 0, 0, 0);
        }
    }

    // ---- store: row = n0 + 4*g + reg, col = 16*f + cl ----
    int rbase = n0 + 4 * g;
#pragma unroll
    for (int j = 0; j < 4; ++j) {
        int n = rbase + j;
        if (n < M) {
            u16* zr = z + (size_t)n * OUTF;
#pragma unroll
            for (int f = 0; f < 8; ++f)
                zr[16 * f + cl] = f2bf(acc[f][j]);
        }
    }
}

// ---------------- SpMM: wave-per-row, 16-deep gather pipeline (unchanged) --
// One wave per row; lane owns 2 feats (ushort2 = 4B gather, 256B contiguous
// per wave per edge). Edge records read as wave-uniform int4 (2 records per
// load, 16B-aligned thanks to even row starts) -> scalarized to s_load.
template <bool MASKED>
__device__ __forceinline__ void edge8(const int2* __restrict__ ep, int e, int end,
                                      const u16* __restrict__ zin, int f,
                                      float2* __restrict__ acc) {
    int2 p[8];
#pragma unroll
    for (int i = 0; i < 8; ++i) {
        int idx = MASKED ? ((e + i < end) ? e + i : end - 1) : (e + i);
        p[i] = ep[idx];
    }
    ushort2 zb[8];
#pragma unroll
    for (int i = 0; i < 8; ++i)
        zb[i] = *(const ushort2*)(zin + (size_t)p[i].x * OUTF + f);
#pragma unroll
    for (int i = 0; i < 8; ++i) {
        float v = __int_as_float(p[i].y);
        if (MASKED) v = (e + i < end) ? v : 0.f;
        acc[i & 3].x += v * bf2f(zb[i].x);
        acc[i & 3].y += v * bf2f(zb[i].y);
    }
}

template <bool OUT_BF16>
__global__ __launch_bounds__(256) void spmm_kernel(const int* __restrict__ rowptr,
                                                   const int* __restrict__ rowcnt,
                                                   const int2* __restrict__ epart,
                                                   const u16* __restrict__ zin,
                                                   void* __restrict__ zout, int M) {
    int r = blockIdx.x * 4 + (threadIdx.x >> 6);
    if (r >= M) return;
    int lane = threadIdx.x & 63;
    int f    = lane * 2;

    int start = __builtin_amdgcn_readfirstlane(rowptr[r]);
    int n     = __builtin_amdgcn_readfirstlane(rowcnt[r]);
    int end   = start + n;

    float2 acc[4] = {{0.f,0.f},{0.f,0.f},{0.f,0.f},{0.f,0.f}};
    int e = start;
    for (; e + 16 <= end; e += 16) {
        int4 q[8];
#pragma unroll
        for (int j = 0; j < 8; ++j) q[j] = *((const int4*)(epart + e) + j);
        __builtin_amdgcn_sched_barrier(0);
        ushort2 zb[16];
#pragma unroll
        for (int j = 0; j < 8; ++j) {
            zb[2*j]   = *(const ushort2*)(zin + (size_t)q[j].x * OUTF + f);
            zb[2*j+1] = *(const ushort2*)(zin + (size_t)q[j].z * OUTF + f);
        }
        __builtin_amdgcn_sched_barrier(0);
#pragma unroll
        for (int j = 0; j < 8; ++j) {
            float v0 = __int_as_float(q[j].y);
            float v1 = __int_as_float(q[j].w);
            acc[(2*j)   & 3].x += v0 * bf2f(zb[2*j].x);
            acc[(2*j)   & 3].y += v0 * bf2f(zb[2*j].y);
            acc[(2*j+1) & 3].x += v1 * bf2f(zb[2*j+1].x);
            acc[(2*j+1) & 3].y += v1 * bf2f(zb[2*j+1].y);
        }
    }
    for (; e < end; e += 8) edge8<true>(epart, e, end, zin, f, acc);

    float sx = (acc[0].x + acc[1].x) + (acc[2].x + acc[3].x);
    float sy = (acc[0].y + acc[1].y) + (acc[2].y + acc[3].y);
    if (OUT_BF16) {
        ushort2 o; o.x = f2bf(sx); o.y = f2bf(sy);
        *(ushort2*)((u16*)zout + (size_t)r * OUTF + f) = o;
    } else {
        *(float2*)((float*)zout + (size_t)r * OUTF + f) = make_float2(sx, sy);
    }
}

// ---------------- launch ----------------

extern "C" void kernel_launch(void* const* d_in, const int* in_sizes, int n_in,
                              void* d_out, int out_size, void* d_ws, size_t ws_size,
                              hipStream_t stream) {
    const float* x    = (const float*)d_in[0];
    const int*   row  = (const int*)d_in[1];
    const int*   col  = (const int*)d_in[2];
    const float* vals = (const float*)d_in[3];
    const float* W    = (const float*)d_in[4];
    const float* b    = (const float*)d_in[5];
    float* out = (float*)d_out;

    const int M = in_sizes[0] / INF;     // 100000
    const int E = in_sizes[1];           // 3200000

    // workspace layout (Wbf and epart 16B-aligned: wconv does ushort4 stores,
    // gemm staging does bf16x8 loads, spmm does int4 loads)
    u16*   zb0    = (u16*)d_ws;                         // M*OUTF bf16 (25.6MB)
    u16*   zb1    = zb0 + (size_t)M * OUTF;             // M*OUTF bf16
    int*   rowptr = (int*)(zb1 + (size_t)M * OUTF);     // M
    int*   rowcnt = rowptr + M;                         // M (= degree array)
    int*   cursor = rowcnt + M;                         // M
    int*   btot   = cursor + M;                         // NSB block totals
    size_t wb_ofs = (size_t)((char*)(btot + NSB) - (char*)d_ws);
    wb_ofs = (wb_ofs + 15) & ~(size_t)15;
    u16*   Wbf    = (u16*)((char*)d_ws + wb_ofs);       // 128*256 bf16 (64KB), 16B-aligned
    size_t ep_ofs = wb_ofs + (size_t)OUTF * INF * sizeof(u16);
    ep_ofs = (ep_ofs + 15) & ~(size_t)15;
    int2*  epart  = (int2*)((char*)d_ws + ep_ofs);      // E+M records (~26.4MB), 16B-aligned

    // 0. W -> bf16 (once)
    wconv_kernel<<<(OUTF * INF) / 1024, 256, 0, stream>>>(W, Wbf);

    // 1. CSR build: count -> scan (3 stages) -> scatter
    hipMemsetAsync(rowcnt, 0, (size_t)M * sizeof(int), stream);
    int egrid = (E + 1023) / 1024;
    count_kernel<<<egrid, 256, 0, stream>>>(row, rowcnt, E);
    scan1_kernel<<<NSB, 256, 0, stream>>>(rowcnt, rowptr, btot, M);
    scan2_kernel<<<1, 128, 0, stream>>>(btot);
    scan3_kernel<<<NSB, 256, 0, stream>>>(rowptr, cursor, btot, M);
    scatter_kernel<<<egrid, 256, 0, stream>>>(row, col, vals, cursor, epart, E);

    // 2. linear: zb0 = bf16(x W^T + b) via MFMA
    gemm_mfma_kernel<<<(M + 63) / 64, 256, 0, stream>>>(x, Wbf, b, zb0, M);

    // 3. three SpMM layers: bf16 staging, fp32 final
    int sgrid = (M + 3) / 4;
    spmm_kernel<true ><<<sgrid, 256, 0, stream>>>(rowptr, rowcnt, epart, zb0, (void*)zb1, M);  // L1
    spmm_kernel<true ><<<sgrid, 256, 0, stream>>>(rowptr, rowcnt, epart, zb1, (void*)zb0, M);  // L2
    spmm_kernel<false><<<sgrid, 256, 0, stream>>>(rowptr, rowcnt, epart, zb0, (void*)out, M);  // L3
}

// Round 7
// 610.206 us; speedup vs baseline: 1.4944x; 1.4944x over previous
//
#include <hip/hip_runtime.h>
#include <hip/hip_bf16.h>

// Problem constants (fixed by the reference's setup_inputs)
#define NNODES   100000
#define INF      256
#define OUTF     128
#define NLAYERS  3        // n_layers input is a device scalar, constant 3 per spec

#define RPB   196         // rows per bucket (row_local in bits 17..24; col < 2^17)
#define NBKT  511         // ceil(100000 / 196)
#define CAP   7168        // bucket capacity: mean 6272 + ~9 sigma incl. row padding
#define EPB   8192        // edges per partition block (16 rec/bucket/block ~ full line)

typedef unsigned short u16;

typedef __attribute__((ext_vector_type(8))) __bf16 bf16x8;
typedef __attribute__((ext_vector_type(4))) float  f32x4;

__device__ __forceinline__ float bf2f(u16 u) {
    union { unsigned int i; float f; } c; c.i = ((unsigned int)u) << 16; return c.f;
}
__device__ __forceinline__ u16 f2bf(float f) {   // round-to-nearest-even
    union { float f; unsigned int i; } c; c.f = f;
    unsigned int lsb = (c.i >> 16) & 1;
    return (u16)((c.i + 0x7FFF + lsb) >> 16);
}

// ---------------- stage 0: W fp32 -> bf16 (once) ----------------
__global__ __launch_bounds__(256) void wconv_kernel(const float* __restrict__ W,
                                                    u16* __restrict__ Wbf) {
    int i = (blockIdx.x * 256 + threadIdx.x) * 4;
    float4 a = *(const float4*)(W + i);
    ushort4 o;
    o.x = f2bf(a.x); o.y = f2bf(a.y); o.z = f2bf(a.z); o.w = f2bf(a.w);
    *(ushort4*)(Wbf + i) = o;    // Wbf is 16B-aligned (see kernel_launch layout)
}

// ---------------- stage 1: bucket partition ----------------
// int4-quad scans (4x shorter latency chains); EPB=8192 so each block writes
// ~16 contiguous records (128B ~ full line) per bucket -> minimal RFO amp.
__global__ __launch_bounds__(256) void partition_kernel(
    const int* __restrict__ row, const int* __restrict__ col,
    const float* __restrict__ vals, int* __restrict__ alloc,
    int2* __restrict__ epart, int E)
{
    __shared__ int hist[NBKT];
    __shared__ int gbase[NBKT];
    int tid = threadIdx.x;
    int e0  = blockIdx.x * EPB;

    for (int i = tid; i < NBKT; i += 256) hist[i] = 0;
    __syncthreads();
    // E is a multiple of 4 and quads are 4-aligned -> each quad fully in or out
    for (int i = tid * 4; i < EPB; i += 1024) {
        int e = e0 + i;
        if (e < E) {
            int4 r4 = *(const int4*)(row + e);
            atomicAdd(&hist[r4.x / RPB], 1);
            atomicAdd(&hist[r4.y / RPB], 1);
            atomicAdd(&hist[r4.z / RPB], 1);
            atomicAdd(&hist[r4.w / RPB], 1);
        }
    }
    __syncthreads();
    for (int i = tid; i < NBKT; i += 256) {
        int c = hist[i];
        gbase[i] = c ? atomicAdd(&alloc[i], c) : 0;
    }
    __syncthreads();
    for (int i = tid; i < NBKT; i += 256) hist[i] = 0;   // reuse as cursor
    __syncthreads();
    for (int i = tid * 4; i < EPB; i += 1024) {
        int e = e0 + i;
        if (e < E) {
            int4   r4 = *(const int4*)(row + e);
            int4   c4 = *(const int4*)(col + e);
            float4 v4 = *(const float4*)(vals + e);
            int   rr[4] = {r4.x, r4.y, r4.z, r4.w};
            int   cc[4] = {c4.x, c4.y, c4.z, c4.w};
            float vv[4] = {v4.x, v4.y, v4.z, v4.w};
#pragma unroll
            for (int t = 0; t < 4; ++t) {
                int b    = rr[t] / RPB;
                int lofs = atomicAdd(&hist[b], 1);
                epart[(size_t)b * CAP + gbase[b] + lofs] =
                    make_int2(cc[t] | ((rr[t] - b * RPB) << 17), __float_as_int(vv[t]));
            }
        }
    }
}

// ---------------- stage 2: per-bucket row grouping (in place) ----------------
// Row segments start at EVEN record offsets (16B-aligned) so spmm can use
// int4 loads on edge records. Pads hold stale data, never read (rowcnt bounds).
__global__ __launch_bounds__(256) void bucket_scatter_kernel(
    const int* __restrict__ alloc, int2* __restrict__ epart,
    int* __restrict__ rowptr, int* __restrict__ rowcnt, int M)
{
    int b = blockIdx.x;
    int n = alloc[b];
    int2* src = epart + (size_t)b * CAP;
    __shared__ int2 stage[CAP];       // 57344 B
    __shared__ int  hist[256];
    __shared__ int  excl[256];
    __shared__ int  wofs[RPB];
    int tid = threadIdx.x;

    for (int i = tid; i < n; i += 256) stage[i] = src[i];
    hist[tid] = 0;
    __syncthreads();
    for (int i = tid; i < n; i += 256) atomicAdd(&hist[stage[i].x >> 17], 1);
    __syncthreads();
    int v = hist[tid];
    int w = (v + 1) & ~1;                          // pad each row to even count
    excl[tid] = w;
    __syncthreads();
    for (int off = 1; off < 256; off <<= 1) {      // Hillis-Steele inclusive
        int t = (tid >= off) ? excl[tid - off] : 0;
        __syncthreads();
        excl[tid] += t;
        __syncthreads();
    }
    int ex = excl[tid] - w;                        // exclusive prefix (padded)
    int r  = b * RPB + tid;
    if (tid < RPB && r < M) {
        rowptr[r] = b * CAP + ex;
        rowcnt[r] = v;
    }
    if (tid < RPB) wofs[tid] = ex;
    __syncthreads();
    for (int i = tid; i < n; i += 256) {
        int2 p  = stage[i];
        int  rl = p.x >> 17;
        int  pos = atomicAdd(&wofs[rl], 1);
        src[pos] = make_int2(p.x & 0x1FFFF, p.y);
    }
}

// ---------------- dense linear via MFMA: z = bf16(x W^T + b) ----------------
// PERSISTENT version: 512 blocks (2/CU, LDS-capped at 64KB/block) stage the
// full 128x256 bf16 W image into XOR-swizzled LDS ONCE, then grid-stride over
// 64-row tiles (~3 tiles/block) with no further barriers. Round-4 version
// re-staged W per 64 rows (1563x) - staging work was ~24x the MFMA work.
// Fragment maps (gfx950, verified):
//   A: row = lane&15, k = 8*(lane>>4)+e   B: col = lane&15, same k
//   D: col = lane&15, row = 4*(lane>>4)+reg
__global__ __launch_bounds__(256) void gemm_mfma_kernel(
    const float* __restrict__ x, const u16* __restrict__ Wbf,
    const float* __restrict__ b, u16* __restrict__ z, int M, int ntiles)
{
    __shared__ __align__(16) u16 Wl[128 * 256];   // 64 KB bf16, swizzled
    int tid  = threadIdx.x;
    int lane = tid & 63;
    int wv   = tid >> 6;

    // ---- stage Wbf: 128x256 bf16 -> LDS, vectorized (one-time) ----
    {
        int c = tid >> 1;              // row 0..127
        int h = tid & 1;               // half
        const bf16x8* src = (const bf16x8*)(Wbf + c * 256 + h * 128);
        u16* dst = Wl + c * 256;
        int swz = c & 7;               // XOR on 16B-chunk index
#pragma unroll
        for (int t = 0; t < 16; ++t) {
            int j = h * 16 + t;        // chunk index 0..31
            *(bf16x8*)(dst + 8 * (j ^ swz)) = src[t];
        }
    }

    int cl = lane & 15;
    int g  = lane >> 4;
    float bo[8];
#pragma unroll
    for (int f = 0; f < 8; ++f) bo[f] = b[16 * f + cl];   // bias per col-frag

    __syncthreads();                   // W resident from here on; no more barriers

    for (int tile = blockIdx.x; tile < ntiles; tile += gridDim.x) {
        int n0 = tile * 64 + wv * 16;      // this wave's 16-row tile
        int nr = n0 + cl;                  // A-operand row for this lane
        if (nr >= M) nr = M - 1;           // clamp (dup loads ok, stores guarded)
        const float* xrow = x + (size_t)nr * INF + 8 * g;

        f32x4 acc[8];
#pragma unroll
        for (int f = 0; f < 8; ++f) {
            f32x4 a; a[0] = bo[f]; a[1] = bo[f]; a[2] = bo[f]; a[3] = bo[f];
            acc[f] = a;
        }

#pragma unroll
        for (int ks = 0; ks < 8; ++ks) {
            int k0 = ks * 32;
            float4 a0 = ((const float4*)(xrow + k0))[0];
            float4 a1 = ((const float4*)(xrow + k0))[1];
            bf16x8 af;
            af[0] = (__bf16)a0.x; af[1] = (__bf16)a0.y;
            af[2] = (__bf16)a0.z; af[3] = (__bf16)a0.w;
            af[4] = (__bf16)a1.x; af[5] = (__bf16)a1.y;
            af[6] = (__bf16)a1.z; af[7] = (__bf16)a1.w;
#pragma unroll
            for (int f = 0; f < 8; ++f) {
                int c  = 16 * f + cl;
                int ke = (k0 + 8 * g) ^ ((c & 7) << 3);
                bf16x8 bfr = *(const bf16x8*)(Wl + c * 256 + ke);
                acc[f] = __builtin_amdgcn_mfma_f32_16x16x32_bf16(af, bfr, acc[f], 0, 0, 0);
            }
        }

        // ---- store: row = n0 + 4*g + reg, col = 16*f + cl ----
        int rbase = n0 + 4 * g;
#pragma unroll
        for (int j = 0; j < 4; ++j) {
            int n = rbase + j;
            if (n < M) {
                u16* zr = z + (size_t)n * OUTF;
#pragma unroll
                for (int f = 0; f < 8; ++f)
                    zr[16 * f + cl] = f2bf(acc[f][j]);
            }
        }
    }
}

// ---------------- SpMM: wave-per-row, 16-deep gather pipeline (unchanged) --
// One wave per row; lane owns 2 feats (ushort2 = 4B gather, 256B contiguous
// per wave per edge). Edge records read as wave-uniform int4 (2 records per
// load, 16B-aligned thanks to even row starts) -> scalarized to s_load.
template <bool MASKED>
__device__ __forceinline__ void edge8(const int2* __restrict__ ep, int e, int end,
                                      const u16* __restrict__ zin, int f,
                                      float2* __restrict__ acc) {
    int2 p[8];
#pragma unroll
    for (int i = 0; i < 8; ++i) {
        int idx = MASKED ? ((e + i < end) ? e + i : end - 1) : (e + i);
        p[i] = ep[idx];
    }
    ushort2 zb[8];
#pragma unroll
    for (int i = 0; i < 8; ++i)
        zb[i] = *(const ushort2*)(zin + (size_t)p[i].x * OUTF + f);
#pragma unroll
    for (int i = 0; i < 8; ++i) {
        float v = __int_as_float(p[i].y);
        if (MASKED) v = (e + i < end) ? v : 0.f;
        acc[i & 3].x += v * bf2f(zb[i].x);
        acc[i & 3].y += v * bf2f(zb[i].y);
    }
}

template <bool OUT_BF16>
__global__ __launch_bounds__(256) void spmm_kernel(const int* __restrict__ rowptr,
                                                   const int* __restrict__ rowcnt,
                                                   const int2* __restrict__ epart,
                                                   const u16* __restrict__ zin,
                                                   void* __restrict__ zout, int M) {
    int r = blockIdx.x * 4 + (threadIdx.x >> 6);
    if (r >= M) return;
    int lane = threadIdx.x & 63;
    int f    = lane * 2;

    int start = __builtin_amdgcn_readfirstlane(rowptr[r]);
    int n     = __builtin_amdgcn_readfirstlane(rowcnt[r]);
    int end   = start + n;

    float2 acc[4] = {{0.f,0.f},{0.f,0.f},{0.f,0.f},{0.f,0.f}};
    int e = start;
    for (; e + 16 <= end; e += 16) {
        int4 q[8];
#pragma unroll
        for (int j = 0; j < 8; ++j) q[j] = *((const int4*)(epart + e) + j);
        __builtin_amdgcn_sched_barrier(0);
        ushort2 zb[16];
#pragma unroll
        for (int j = 0; j < 8; ++j) {
            zb[2*j]   = *(const ushort2*)(zin + (size_t)q[j].x * OUTF + f);
            zb[2*j+1] = *(const ushort2*)(zin + (size_t)q[j].z * OUTF + f);
        }
        __builtin_amdgcn_sched_barrier(0);
#pragma unroll
        for (int j = 0; j < 8; ++j) {
            float v0 = __int_as_float(q[j].y);
            float v1 = __int_as_float(q[j].w);
            acc[(2*j)   & 3].x += v0 * bf2f(zb[2*j].x);
            acc[(2*j)   & 3].y += v0 * bf2f(zb[2*j].y);
            acc[(2*j+1) & 3].x += v1 * bf2f(zb[2*j+1].x);
            acc[(2*j+1) & 3].y += v1 * bf2f(zb[2*j+1].y);
        }
    }
    for (; e < end; e += 8) edge8<true>(epart, e, end, zin, f, acc);

    float sx = (acc[0].x + acc[1].x) + (acc[2].x + acc[3].x);
    float sy = (acc[0].y + acc[1].y) + (acc[2].y + acc[3].y);
    if (OUT_BF16) {
        ushort2 o; o.x = f2bf(sx); o.y = f2bf(sy);
        *(ushort2*)((u16*)zout + (size_t)r * OUTF + f) = o;
    } else {
        *(float2*)((float*)zout + (size_t)r * OUTF + f) = make_float2(sx, sy);
    }
}

// ---------------- launch ----------------

extern "C" void kernel_launch(void* const* d_in, const int* in_sizes, int n_in,
                              void* d_out, int out_size, void* d_ws, size_t ws_size,
                              hipStream_t stream) {
    const float* x    = (const float*)d_in[0];
    const int*   row  = (const int*)d_in[1];
    const int*   col  = (const int*)d_in[2];
    const float* vals = (const float*)d_in[3];
    const float* W    = (const float*)d_in[4];
    const float* b    = (const float*)d_in[5];
    float* out = (float*)d_out;

    const int M = in_sizes[0] / INF;     // 100000
    const int E = in_sizes[1];           // 3200000

    // workspace layout (Wbf and epart 16B-aligned: wconv does ushort4 stores,
    // gemm staging does bf16x8 loads, spmm does int4 loads)
    u16*   zb0    = (u16*)d_ws;                         // M*OUTF bf16 (25.6MB)
    u16*   zb1    = zb0 + (size_t)M * OUTF;             // M*OUTF bf16
    int*   rowptr = (int*)(zb1 + (size_t)M * OUTF);     // M
    int*   rowcnt = rowptr + M;                         // M
    int*   alloc  = rowcnt + M;                         // NBKT
    size_t wb_ofs = (size_t)((char*)(alloc + NBKT) - (char*)d_ws);
    wb_ofs = (wb_ofs + 15) & ~(size_t)15;
    u16*   Wbf    = (u16*)((char*)d_ws + wb_ofs);       // 128*256 bf16 (64KB), 16B-aligned
    size_t ep_ofs = wb_ofs + (size_t)OUTF * INF * sizeof(u16);
    ep_ofs = (ep_ofs + 15) & ~(size_t)15;
    int2*  epart  = (int2*)((char*)d_ws + ep_ofs);      // NBKT*CAP records (~29.3MB), 16B-aligned

    // 0. W -> bf16 (once)
    wconv_kernel<<<(OUTF * INF) / 1024, 256, 0, stream>>>(W, Wbf);

    // 1. CSR build via two-level bucket partition
    hipMemsetAsync(alloc, 0, NBKT * sizeof(int), stream);
    partition_kernel<<<(E + EPB - 1) / EPB, 256, 0, stream>>>(row, col, vals, alloc, epart, E);
    bucket_scatter_kernel<<<NBKT, 256, 0, stream>>>(alloc, epart, rowptr, rowcnt, M);

    // 2. linear: zb0 = bf16(x W^T + b) via persistent-W MFMA (2 blocks/CU)
    int ntiles = (M + 63) / 64;
    gemm_mfma_kernel<<<512, 256, 0, stream>>>(x, Wbf, b, zb0, M, ntiles);

    // 3. three SpMM layers: bf16 staging, fp32 final
    int sgrid = (M + 3) / 4;
    spmm_kernel<true ><<<sgrid, 256, 0, stream>>>(rowptr, rowcnt, epart, zb0, (void*)zb1, M);  // L1
    spmm_kernel<true ><<<sgrid, 256, 0, stream>>>(rowptr, rowcnt, epart, zb1, (void*)zb0, M);  // L2
    spmm_kernel<false><<<sgrid, 256, 0, stream>>>(rowptr, rowcnt, epart, zb0, (void*)out, M);  // L3
}